// Round 2
// baseline (320.727 us; speedup 1.0000x reference)
//
#include <hip/hip_runtime.h>
#include <hip/hip_fp16.h>

// NCC loss, fully fused, R9 (resubmit — previous round failed on container
// acquisition, not on the kernel): occupancy push.
// R8 counters showed latency-bound (MfmaUtil 6%, VALU 36%, Occ 32%) with the
// grid (960 blocks = 3.75/CU) as the residency limiter, NOT throughput.
// R9: DC 40->20 (grid 1920 = 7.5/CU) + packed raw rows RS 20->12 dw
// (LDS 31.2->23.1 KB -> 7 blocks/CU). Packing is safe: taps 24..31 read
// neighbor-row fp16 garbage but SEL[k]=0 for all k>=24 (n15+8<=23), so the
// contribution is exactly 0 (all staged values finite). Chain/ring structure
// unchanged; stage_write+fetch moved before ring_cc so LDS/VMEM issue ahead
// of the VALU-heavy ring block.
// Vols: [B=2][D=160][H=192][W=160] fp32. Out: scalar -mean(cc).

#define B_    2
#define D_    160
#define H_    192
#define W_    160
#define HW_   (H_*W_)

// LDS layout (float-word offsets)
#define RS    12                   // raw row stride: 24 taps fp16 = 12 dw, packed
#define SLS   (24*RS)              // 288: raw slice stride
#define FS    (2*SLS)              // 576: raw field stride (2 slices)
#define ZROW  (5*FS)               // 2880: 16 dw of zeros (A2 OOB-row reads)
#define TMP0  (ZROW + 16)          // 2896: 4 waves x 320
#define TS    20                   // tmp col stride (32 k fp16 = 16 dw, pad->20)
#define HSUM0 (TMP0 + 4*320)       // 4176: 10 chains x 160
#define HCS   160                  // per-(slc,f) hsum block: 16 cols x 10
#define HRS   10                   // hsum col stride (16 h fp16 = 8 dw, pad->10)
#define REDU  (HSUM0 + 10*HCS)     // 5776
#define SMEM  (REDU + 8)           // 5784 dw = 23.1 KB -> 7 blocks/CU
#define DC    20                   // R9: 20 (was 40) -> grid z doubles
#define ZCH   (D_/DC)              // 8 z-chunks per batch
#define NMAC  ((DC+8)/2)           // 14
#define W3I   (1.0f/729.0f)
#define NTOT  9830400.0f

#if __has_builtin(__builtin_amdgcn_rcpf)
#define RCP(x) __builtin_amdgcn_rcpf(x)
#else
#define RCP(x) (1.0f/(x))
#endif
#define LGKM0() asm volatile("s_waitcnt lgkmcnt(0)" ::: "memory")

typedef _Float16 half8 __attribute__((ext_vector_type(8)));
typedef float    f32x4 __attribute__((ext_vector_type(4)));
#define MFMA16(a,b,c) __builtin_amdgcn_mfma_f32_16x16x32_f16((a),(b),(c),0,0,0)

struct __align__(8) HP { __half2 a, b; };   // 4 fp16 = one b64 LDS word-pair

__global__ __launch_bounds__(256, 6) void ncc_fused(const float* __restrict__ gI,
                                                    const float* __restrict__ gJ,
                                                    float* __restrict__ out)
{
  __shared__ __align__(16) float sm[SMEM];
  const int tid  = threadIdx.x;
  const int lane = tid & 63;
  const int Q    = tid >> 6;
  const int n15  = lane & 15;          // MFMA: A-row m / B-col n / D-col
  const int q4   = lane >> 4;          // MFMA: k-group / D-row quad
  const int w0   = blockIdx.x * 16;
  const int h0   = blockIdx.y * 16;
  const int bz   = blockIdx.z;
  const int bb   = bz / ZCH;
  const int d_lo = (bz % ZCH) * DC;

  // zero raw region + zrow (invalid halo stays 0 forever)
  for (int i = tid; i < TMP0; i += 256) sm[i] = 0.f;

  // shared banded selection fragment: SEL[j] = [n15 <= k <= n15+8], k = 8*q4+j
  half8 SEL;
  #pragma unroll
  for (int j = 0; j < 8; ++j) {
    const int k = 8*q4 + j;
    SEL[j] = (k >= n15 && k <= n15 + 8) ? (_Float16)1 : (_Float16)0;
  }

  // ---------- staging: 288 tasks = 2 slc x 24 r x 6 quads ----------
  bool val0 = false, val1 = false;
  int  lo0 = 0, lo1 = 0, sc0 = 0, sc1 = 0;
  const float *pi0 = gI, *pj0 = gJ, *pi1 = gI, *pj1 = gJ;
  {
    auto prep = [&](int t, bool& val, int& lo, int& sc,
                    const float*& pi, const float*& pj) {
      if (t >= 288) { val = false; return; }
      sc = t / 144;
      const int u = t - sc*144;
      const int r = u / 6, c = u - r*6;
      const int gh = h0 - 4 + r, gw = w0 - 4 + 4*c;
      val = ((unsigned)gh < (unsigned)H_) && (gw >= 0) && (gw + 3 < W_);
      lo  = sc*SLS + r*RS + 2*c;
      const long off = ((long)(bb*D_ + (d_lo - 4 + sc))*H_ + gh)*(long)W_ + gw;
      pi = gI + off; pj = gJ + off;
    };
    prep(tid, val0, lo0, sc0, pi0, pj0);
    prep((tid >= 224) ? tid + 32 : 512, val1, lo1, sc1, pi1, pj1);
  }

  // ---------- chain bases: wave Q handles c = Q, Q+4, Q+8 (<10) ----------
  int rb_[3], hb_[3];
  #pragma unroll
  for (int i = 0; i < 3; ++i) {
    int c = Q + 4*i; if (c > 9) c = 9;          // clamped entry unused
    rb_[i] = (c % 5)*FS + (c / 5)*SLS;
    hb_[i] = HSUM0 + c*HCS;
  }
  const int tb  = TMP0 + Q*320 + n15*TS;
  const int a1r = n15*RS + 4*q4;
  const int a2r = (n15 < 8) ? ((16 + n15)*RS + 4*q4) : -1;
  const int zr  = ZROW + 4*q4;

  // ---------- ring: thread owns (h = tid>>4, w = tid&15) ----------
  const int rh = tid >> 4, rw = tid & 15;
  const int rbase = HSUM0 + rw*HRS + (rh >> 1);
  const int rsh   = (rh & 1) * 16;

  float ring[5][9], S[5];
  #pragma unroll
  for (int f = 0; f < 5; ++f) {
    S[f] = 0.f;
    #pragma unroll
    for (int k = 0; k < 9; ++k) ring[f][k] = 0.f;
  }
  float acc = 0.f;

  // ---------- global prefetch ----------
  float4 f0i = {0,0,0,0}, f0j = {0,0,0,0}, f1i = {0,0,0,0}, f1j = {0,0,0,0};
  auto fetch = [&](int sbase) {
    if (val0 && (unsigned)(sbase + sc0) < (unsigned)D_) {
      f0i = *(const float4*)pi0; f0j = *(const float4*)pj0;
    } else { f0i = make_float4(0,0,0,0); f0j = make_float4(0,0,0,0); }
    pi0 += 2*HW_; pj0 += 2*HW_;
    if (val1 && (unsigned)(sbase + sc1) < (unsigned)D_) {
      f1i = *(const float4*)pi1; f1j = *(const float4*)pj1;
    } else { f1i = make_float4(0,0,0,0); f1j = make_float4(0,0,0,0); }
    pi1 += 2*HW_; pj1 += 2*HW_;
  };

  auto stage_one = [&](int lo, float4 fi, float4 fj) {
    const __half2 i01 = __floats2half2_rn(fi.x, fi.y);
    const __half2 i23 = __floats2half2_rn(fi.z, fi.w);
    const __half2 j01 = __floats2half2_rn(fj.x, fj.y);
    const __half2 j23 = __floats2half2_rn(fj.z, fj.w);
    HP hI; hI.a = i01; hI.b = i23;
    HP hJ; hJ.a = j01; hJ.b = j23;
    HP h2; h2.a = __hmul2(i01, i01); h2.b = __hmul2(i23, i23);
    HP h3; h3.a = __hmul2(j01, j01); h3.b = __hmul2(j23, j23);
    HP h4; h4.a = __hmul2(i01, j01); h4.b = __hmul2(i23, j23);
    *(HP*)&sm[lo]        = hI;
    *(HP*)&sm[lo +   FS] = hJ;
    *(HP*)&sm[lo + 2*FS] = h2;
    *(HP*)&sm[lo + 3*FS] = h3;
    *(HP*)&sm[lo + 4*FS] = h4;
  };
  auto stage_write = [&]() {
    if (val0) stage_one(lo0, f0i, f0j);
    if (val1) stage_one(lo1, f1i, f1j);
  };

  // ---------- one chain: raw field slice -> hsum (2 w-MFMAs + 1 h-MFMA) ----
  auto chain = [&](int rb, int hb) {
    const half8 A1 = *(const half8*)&sm[rb + a1r];
    const half8 A2 = (a2r >= 0) ? *(const half8*)&sm[rb + a2r]
                                : *(const half8*)&sm[zr];
    const f32x4 z = {0.f, 0.f, 0.f, 0.f};
    const f32x4 d1 = MFMA16(A1, SEL, z);      // wsum rows 0..15
    const f32x4 d2 = MFMA16(A2, SEL, z);      // wsum rows 16..23 (24..31 = 0)
    HP p1; p1.a = __floats2half2_rn(d1[0], d1[1]); p1.b = __floats2half2_rn(d1[2], d1[3]);
    HP p2; p2.a = __floats2half2_rn(d2[0], d2[1]); p2.b = __floats2half2_rn(d2[2], d2[3]);
    *(HP*)&sm[tb + 2*q4]     = p1;            // tmp col n15, k = 4q4..4q4+3
    *(HP*)&sm[tb + 8 + 2*q4] = p2;            // k = 16+4q4..19+4q4
    LGKM0();                                  // tmp visible to own wave
    const half8 Bh = *(const half8*)&sm[tb + 4*q4];   // col n15, k = 8q4..8q4+7
    const f32x4 dh = MFMA16(SEL, Bh, z);      // hsum[m = h][n = w]
    HP ph; ph.a = __floats2half2_rn(dh[0], dh[1]); ph.b = __floats2half2_rn(dh[2], dh[3]);
    *(HP*)&sm[hb + n15*HRS + 2*q4] = ph;      // col w = n15, h = 4q4..4q4+3
  };

  auto h2ext = [&](int addr) -> float {
    const unsigned u = *(const unsigned*)&sm[addr];
    return __half2float(__ushort_as_half((unsigned short)(u >> rsh)));
  };
  auto ring_cc = [&](int m) {
    float nA[5], nB[5];
    #pragma unroll
    for (int f = 0; f < 5; ++f) {
      nA[f] = h2ext(rbase + f*HCS);           // slice A = chain f
      nB[f] = h2ext(rbase + (5 + f)*HCS);     // slice B = chain 5+f
    }
    float SA[5], SB[5];
    #pragma unroll
    for (int f = 0; f < 5; ++f) {
      SA[f] = S[f]  + nA[f] - ring[f][8];
      SB[f] = SA[f] + nB[f] - ring[f][7];
      S[f]  = SB[f];
      #pragma unroll
      for (int k = 8; k >= 2; --k) ring[f][k] = ring[f][k-2];
      ring[f][1] = nA[f]; ring[f][0] = nB[f];
    }
    if (m >= 4) {
      {
        const float cr = SA[4] - SA[0]*SA[1]*W3I;
        const float vi = SA[2] - SA[0]*SA[0]*W3I;
        const float vj = SA[3] - SA[1]*SA[1]*W3I;
        acc += cr*cr * RCP(vi*vj + 1e-5f);
      }
      {
        const float cr = SB[4] - SB[0]*SB[1]*W3I;
        const float vi = SB[2] - SB[0]*SB[0]*W3I;
        const float vj = SB[3] - SB[1]*SB[1]*W3I;
        acc += cr*cr * RCP(vi*vj + 1e-5f);
      }
    }
  };

  fetch(d_lo - 4);          // macro 0 slices
  __syncthreads();          // zero-init visible
  stage_write();            // raw macro 0
  fetch(d_lo - 2);          // macro 1 slices
  __syncthreads();          // raw 0 ready

  for (int m = 0; m < NMAC; ++m) {
    chain(rb_[0], hb_[0]);
    chain(rb_[1], hb_[1]);
    if (Q < 2) chain(rb_[2], hb_[2]);
    __syncthreads();                       // hsum (all waves) ready
    if (m + 1 < NMAC) { stage_write(); fetch(d_lo + 2*m); }  // raw m+1; regs m+2
    ring_cc(m);
    __syncthreads();                       // raw m+1 ready; hsum consumed
  }

  // ---- block reduction -> single atomic ----
  float v = acc;
  #pragma unroll
  for (int off = 32; off > 0; off >>= 1)
    v += __shfl_down(v, off, 64);
  if (lane == 0) sm[REDU + Q] = v;
  __syncthreads();
  if (tid == 0) {
    const float t = sm[REDU] + sm[REDU+1] + sm[REDU+2] + sm[REDU+3];
    atomicAdd(out, -t / NTOT);
  }
}

extern "C" void kernel_launch(void* const* d_in, const int* in_sizes, int n_in,
                              void* d_out, int out_size, void* d_ws, size_t ws_size,
                              hipStream_t stream) {
  const float* J = (const float*)d_in[0];  // y_pred
  const float* I = (const float*)d_in[1];  // y_true (cc symmetric in I,J)
  float* outp = (float*)d_out;
  hipMemsetAsync(d_out, 0, sizeof(float), stream);
  dim3 grid(W_/16, H_/16, B_*ZCH);         // 10 x 12 x 16 = 1920 blocks
  ncc_fused<<<grid, dim3(256), 0, stream>>>(I, J, outp);
}

// Round 3
// 164.605 us; speedup vs baseline: 1.9485x; 1.9485x over previous
//
#include <hip/hip_runtime.h>
#include <hip/hip_fp16.h>

// NCC loss, fully fused, R10: un-spill + 7 blocks/CU.
// R9 post-mortem: __launch_bounds__(256,6) forced VGPR 60->40 -> ring state
// spilled to scratch (WRITE_SIZE 30KB->287MB per dispatch, 67->243us). The
// occupancy thesis was never tested un-spilled. R10: bounds back to (256,4)
// (natural ~60 VGPR <= 64 -> 8-waves/SIMD HW bucket, no spill); TS 20->18
// shaves LDS to 22.1KB (23040B rounded) -> 7 blocks/CU LDS cap. Grid stays
// 1920 (DC=20, RS=12 packed raw rows from R9 — both kept).
// Vols: [B=2][D=160][H=192][W=160] fp32. Out: scalar -mean(cc).

#define B_    2
#define D_    160
#define H_    192
#define W_    160
#define HW_   (H_*W_)

// LDS layout (float-word offsets)
#define RS    12                   // raw row stride: 24 taps fp16 = 12 dw, packed
#define SLS   (24*RS)              // 288: raw slice stride
#define FS    (2*SLS)              // 576: raw field stride (2 slices)
#define ZROW  (5*FS)               // 2880: 16 dw of zeros (A2 OOB-row reads)
#define TMP0  (ZROW + 16)          // 2896: 4 waves x 288
#define TS    18                   // tmp col stride (32 k fp16 = 16 dw, pad->18)
#define HSUM0 (TMP0 + 4*16*TS)     // 4048: 10 chains x 160
#define HCS   160                  // per-(slc,f) hsum block: 16 cols x 10
#define HRS   10                   // hsum col stride (16 h fp16 = 8 dw, pad->10)
#define REDU  (HSUM0 + 10*HCS)     // 5648
#define SMEM  (REDU + 8)           // 5656 dw = 22.6 KB -> 7 blocks/CU
#define DC    20                   // z-chunk depth (grid z = 16)
#define ZCH   (D_/DC)              // 8 z-chunks per batch
#define NMAC  ((DC+8)/2)           // 14
#define W3I   (1.0f/729.0f)
#define NTOT  9830400.0f

#if __has_builtin(__builtin_amdgcn_rcpf)
#define RCP(x) __builtin_amdgcn_rcpf(x)
#else
#define RCP(x) (1.0f/(x))
#endif
#define LGKM0() asm volatile("s_waitcnt lgkmcnt(0)" ::: "memory")

typedef _Float16 half8 __attribute__((ext_vector_type(8)));
typedef float    f32x4 __attribute__((ext_vector_type(4)));
#define MFMA16(a,b,c) __builtin_amdgcn_mfma_f32_16x16x32_f16((a),(b),(c),0,0,0)

struct __align__(8) HP { __half2 a, b; };   // 4 fp16 = one b64 LDS word-pair

__global__ __launch_bounds__(256, 4) void ncc_fused(const float* __restrict__ gI,
                                                    const float* __restrict__ gJ,
                                                    float* __restrict__ out)
{
  __shared__ __align__(16) float sm[SMEM];
  const int tid  = threadIdx.x;
  const int lane = tid & 63;
  const int Q    = tid >> 6;
  const int n15  = lane & 15;          // MFMA: A-row m / B-col n / D-col
  const int q4   = lane >> 4;          // MFMA: k-group / D-row quad
  const int w0   = blockIdx.x * 16;
  const int h0   = blockIdx.y * 16;
  const int bz   = blockIdx.z;
  const int bb   = bz / ZCH;
  const int d_lo = (bz % ZCH) * DC;

  // zero raw region + zrow (invalid halo stays 0 forever)
  for (int i = tid; i < TMP0; i += 256) sm[i] = 0.f;

  // shared banded selection fragment: SEL[j] = [n15 <= k <= n15+8], k = 8*q4+j
  half8 SEL;
  #pragma unroll
  for (int j = 0; j < 8; ++j) {
    const int k = 8*q4 + j;
    SEL[j] = (k >= n15 && k <= n15 + 8) ? (_Float16)1 : (_Float16)0;
  }

  // ---------- staging: 288 tasks = 2 slc x 24 r x 6 quads ----------
  bool val0 = false, val1 = false;
  int  lo0 = 0, lo1 = 0, sc0 = 0, sc1 = 0;
  const float *pi0 = gI, *pj0 = gJ, *pi1 = gI, *pj1 = gJ;
  {
    auto prep = [&](int t, bool& val, int& lo, int& sc,
                    const float*& pi, const float*& pj) {
      if (t >= 288) { val = false; return; }
      sc = t / 144;
      const int u = t - sc*144;
      const int r = u / 6, c = u - r*6;
      const int gh = h0 - 4 + r, gw = w0 - 4 + 4*c;
      val = ((unsigned)gh < (unsigned)H_) && (gw >= 0) && (gw + 3 < W_);
      lo  = sc*SLS + r*RS + 2*c;
      const long off = ((long)(bb*D_ + (d_lo - 4 + sc))*H_ + gh)*(long)W_ + gw;
      pi = gI + off; pj = gJ + off;
    };
    prep(tid, val0, lo0, sc0, pi0, pj0);
    prep((tid >= 224) ? tid + 32 : 512, val1, lo1, sc1, pi1, pj1);
  }

  // ---------- chain bases: wave Q handles c = Q, Q+4, Q+8 (<10) ----------
  int rb_[3], hb_[3];
  #pragma unroll
  for (int i = 0; i < 3; ++i) {
    int c = Q + 4*i; if (c > 9) c = 9;          // clamped entry unused
    rb_[i] = (c % 5)*FS + (c / 5)*SLS;
    hb_[i] = HSUM0 + c*HCS;
  }
  const int tb  = TMP0 + Q*(16*TS) + n15*TS;
  const int a1r = n15*RS + 4*q4;
  const int a2r = (n15 < 8) ? ((16 + n15)*RS + 4*q4) : -1;
  const int zr  = ZROW + 4*q4;

  // ---------- ring: thread owns (h = tid>>4, w = tid&15) ----------
  const int rh = tid >> 4, rw = tid & 15;
  const int rbase = HSUM0 + rw*HRS + (rh >> 1);
  const int rsh   = (rh & 1) * 16;

  float ring[5][9], S[5];
  #pragma unroll
  for (int f = 0; f < 5; ++f) {
    S[f] = 0.f;
    #pragma unroll
    for (int k = 0; k < 9; ++k) ring[f][k] = 0.f;
  }
  float acc = 0.f;

  // ---------- global prefetch ----------
  float4 f0i = {0,0,0,0}, f0j = {0,0,0,0}, f1i = {0,0,0,0}, f1j = {0,0,0,0};
  auto fetch = [&](int sbase) {
    if (val0 && (unsigned)(sbase + sc0) < (unsigned)D_) {
      f0i = *(const float4*)pi0; f0j = *(const float4*)pj0;
    } else { f0i = make_float4(0,0,0,0); f0j = make_float4(0,0,0,0); }
    pi0 += 2*HW_; pj0 += 2*HW_;
    if (val1 && (unsigned)(sbase + sc1) < (unsigned)D_) {
      f1i = *(const float4*)pi1; f1j = *(const float4*)pj1;
    } else { f1i = make_float4(0,0,0,0); f1j = make_float4(0,0,0,0); }
    pi1 += 2*HW_; pj1 += 2*HW_;
  };

  auto stage_one = [&](int lo, float4 fi, float4 fj) {
    const __half2 i01 = __floats2half2_rn(fi.x, fi.y);
    const __half2 i23 = __floats2half2_rn(fi.z, fi.w);
    const __half2 j01 = __floats2half2_rn(fj.x, fj.y);
    const __half2 j23 = __floats2half2_rn(fj.z, fj.w);
    HP hI; hI.a = i01; hI.b = i23;
    HP hJ; hJ.a = j01; hJ.b = j23;
    HP h2; h2.a = __hmul2(i01, i01); h2.b = __hmul2(i23, i23);
    HP h3; h3.a = __hmul2(j01, j01); h3.b = __hmul2(j23, j23);
    HP h4; h4.a = __hmul2(i01, j01); h4.b = __hmul2(i23, j23);
    *(HP*)&sm[lo]        = hI;
    *(HP*)&sm[lo +   FS] = hJ;
    *(HP*)&sm[lo + 2*FS] = h2;
    *(HP*)&sm[lo + 3*FS] = h3;
    *(HP*)&sm[lo + 4*FS] = h4;
  };
  auto stage_write = [&]() {
    if (val0) stage_one(lo0, f0i, f0j);
    if (val1) stage_one(lo1, f1i, f1j);
  };

  // ---------- one chain: raw field slice -> hsum (2 w-MFMAs + 1 h-MFMA) ----
  auto chain = [&](int rb, int hb) {
    const half8 A1 = *(const half8*)&sm[rb + a1r];
    const half8 A2 = (a2r >= 0) ? *(const half8*)&sm[rb + a2r]
                                : *(const half8*)&sm[zr];
    const f32x4 z = {0.f, 0.f, 0.f, 0.f};
    const f32x4 d1 = MFMA16(A1, SEL, z);      // wsum rows 0..15
    const f32x4 d2 = MFMA16(A2, SEL, z);      // wsum rows 16..23 (24..31 = 0)
    HP p1; p1.a = __floats2half2_rn(d1[0], d1[1]); p1.b = __floats2half2_rn(d1[2], d1[3]);
    HP p2; p2.a = __floats2half2_rn(d2[0], d2[1]); p2.b = __floats2half2_rn(d2[2], d2[3]);
    *(HP*)&sm[tb + 2*q4]     = p1;            // tmp col n15, k = 4q4..4q4+3
    *(HP*)&sm[tb + 8 + 2*q4] = p2;            // k = 16+4q4..19+4q4
    LGKM0();                                  // tmp visible to own wave
    const half8 Bh = *(const half8*)&sm[tb + 4*q4];   // col n15, k = 8q4..8q4+7
    const f32x4 dh = MFMA16(SEL, Bh, z);      // hsum[m = h][n = w]
    HP ph; ph.a = __floats2half2_rn(dh[0], dh[1]); ph.b = __floats2half2_rn(dh[2], dh[3]);
    *(HP*)&sm[hb + n15*HRS + 2*q4] = ph;      // col w = n15, h = 4q4..4q4+3
  };

  auto h2ext = [&](int addr) -> float {
    const unsigned u = *(const unsigned*)&sm[addr];
    return __half2float(__ushort_as_half((unsigned short)(u >> rsh)));
  };
  auto ring_cc = [&](int m) {
    float nA[5], nB[5];
    #pragma unroll
    for (int f = 0; f < 5; ++f) {
      nA[f] = h2ext(rbase + f*HCS);           // slice A = chain f
      nB[f] = h2ext(rbase + (5 + f)*HCS);     // slice B = chain 5+f
    }
    float SA[5], SB[5];
    #pragma unroll
    for (int f = 0; f < 5; ++f) {
      SA[f] = S[f]  + nA[f] - ring[f][8];
      SB[f] = SA[f] + nB[f] - ring[f][7];
      S[f]  = SB[f];
      #pragma unroll
      for (int k = 8; k >= 2; --k) ring[f][k] = ring[f][k-2];
      ring[f][1] = nA[f]; ring[f][0] = nB[f];
    }
    if (m >= 4) {
      {
        const float cr = SA[4] - SA[0]*SA[1]*W3I;
        const float vi = SA[2] - SA[0]*SA[0]*W3I;
        const float vj = SA[3] - SA[1]*SA[1]*W3I;
        acc += cr*cr * RCP(vi*vj + 1e-5f);
      }
      {
        const float cr = SB[4] - SB[0]*SB[1]*W3I;
        const float vi = SB[2] - SB[0]*SB[0]*W3I;
        const float vj = SB[3] - SB[1]*SB[1]*W3I;
        acc += cr*cr * RCP(vi*vj + 1e-5f);
      }
    }
  };

  fetch(d_lo - 4);          // macro 0 slices
  __syncthreads();          // zero-init visible
  stage_write();            // raw macro 0
  fetch(d_lo - 2);          // macro 1 slices
  __syncthreads();          // raw 0 ready

  for (int m = 0; m < NMAC; ++m) {
    chain(rb_[0], hb_[0]);
    chain(rb_[1], hb_[1]);
    if (Q < 2) chain(rb_[2], hb_[2]);
    __syncthreads();                       // hsum (all waves) ready
    if (m + 1 < NMAC) { stage_write(); fetch(d_lo + 2*m); }  // raw m+1; regs m+2
    ring_cc(m);
    __syncthreads();                       // raw m+1 ready; hsum consumed
  }

  // ---- block reduction -> single atomic ----
  float v = acc;
  #pragma unroll
  for (int off = 32; off > 0; off >>= 1)
    v += __shfl_down(v, off, 64);
  if (lane == 0) sm[REDU + Q] = v;
  __syncthreads();
  if (tid == 0) {
    const float t = sm[REDU] + sm[REDU+1] + sm[REDU+2] + sm[REDU+3];
    atomicAdd(out, -t / NTOT);
  }
}

extern "C" void kernel_launch(void* const* d_in, const int* in_sizes, int n_in,
                              void* d_out, int out_size, void* d_ws, size_t ws_size,
                              hipStream_t stream) {
  const float* J = (const float*)d_in[0];  // y_pred
  const float* I = (const float*)d_in[1];  // y_true (cc symmetric in I,J)
  float* outp = (float*)d_out;
  hipMemsetAsync(d_out, 0, sizeof(float), stream);
  dim3 grid(W_/16, H_/16, B_*ZCH);         // 10 x 12 x 16 = 1920 blocks
  ncc_fused<<<grid, dim3(256), 0, stream>>>(I, J, outp);
}

// Round 4
// 147.416 us; speedup vs baseline: 2.1757x; 1.1166x over previous
//
#include <hip/hip_runtime.h>
#include <hip/hip_fp16.h>

// NCC loss, fully fused, R11: kill the tmp-LDS round-trip with permlane swaps.
// R10 post-mortem: doubling available blocks/CU (DC 20, LDS cap 7) left
// occupancy (~35%) and per-macro throughput (2.9->3.1 ns/block-macro)
// unchanged -> NOT wave-starved. LDS pipe is the most-busy resource
// (~64-80%): per macro ~127 wave-level DS ops + 287-493 conflict cycles, and
// each chain serializes on a full lgkmcnt(0) drain around the tmp buffer.
// R11: the tmp transpose (wsum D-layout -> h-MFMA B-fragment) is an
// intra-column shuffle over lanes {n15,+16,+32,+48} == permlane32_swap +
// permlane16_swap (VALU). Removes 2 b64 writes + 1 b128 read + the drain per
// chain (-20% LDS traffic, kills the mid-chain serialization). DC back to 40
// (R10 proved the halo overhead of DC=20 is a pure loss). LDS 18 KB.
// Vols: [B=2][D=160][H=192][W=160] fp32. Out: scalar -mean(cc).

#define B_    2
#define D_    160
#define H_    192
#define W_    160
#define HW_   (H_*W_)

// LDS layout (float-word offsets)
#define RS    12                   // raw row stride: 24 taps fp16 = 12 dw, packed
#define SLS   (24*RS)              // 288: raw slice stride
#define FS    (2*SLS)              // 576: raw field stride (2 slices)
#define ZROW  (5*FS)               // 2880: 16 dw of zeros (A2 OOB-row reads)
#define ZEND  (ZROW + 16)          // 2896: end of zero-init region
#define HSUM0 ZEND                 // 2896: 10 chains x 160
#define HCS   160                  // per-(slc,f) hsum block: 16 cols x 10
#define HRS   10                   // hsum col stride (16 h fp16 = 8 dw, pad->10)
#define REDU  (HSUM0 + 10*HCS)     // 4496
#define SMEM  (REDU + 8)           // 4504 dw = 18.0 KB
#define DC    40                   // R8-proven best halo ratio (grid z = 8)
#define ZCH   (D_/DC)              // 4 z-chunks per batch
#define NMAC  ((DC+8)/2)           // 24
#define W3I   (1.0f/729.0f)
#define NTOT  9830400.0f

#if __has_builtin(__builtin_amdgcn_rcpf)
#define RCP(x) __builtin_amdgcn_rcpf(x)
#else
#define RCP(x) (1.0f/(x))
#endif

typedef _Float16 half8 __attribute__((ext_vector_type(8)));
typedef float    f32x4 __attribute__((ext_vector_type(4)));
typedef unsigned u32x2 __attribute__((ext_vector_type(2)));
#define MFMA16(a,b,c) __builtin_amdgcn_mfma_f32_16x16x32_f16((a),(b),(c),0,0,0)

// permlane swaps: a=VDST, b=VSRC, both updated (ISA: VDST.hi<->VSRC.lo for
// 32-swap; odd<->even 16-groups for 16-swap).
#if __has_builtin(__builtin_amdgcn_permlane32_swap)
#define PL32(a,b) do { u32x2 _s = __builtin_amdgcn_permlane32_swap((a),(b),false,false); \
                       (a)=_s[0]; (b)=_s[1]; } while(0)
#else
#define PL32(a,b) asm volatile("s_nop 1\nv_permlane32_swap_b32 %0, %1" : "+v"(a), "+v"(b))
#endif
#if __has_builtin(__builtin_amdgcn_permlane16_swap)
#define PL16(a,b) do { u32x2 _s = __builtin_amdgcn_permlane16_swap((a),(b),false,false); \
                       (a)=_s[0]; (b)=_s[1]; } while(0)
#else
#define PL16(a,b) asm volatile("s_nop 1\nv_permlane16_swap_b32 %0, %1" : "+v"(a), "+v"(b))
#endif

struct __align__(8) HP { __half2 a, b; };   // 4 fp16 = one b64 LDS word-pair

__global__ __launch_bounds__(256, 4) void ncc_fused(const float* __restrict__ gI,
                                                    const float* __restrict__ gJ,
                                                    float* __restrict__ out)
{
  __shared__ __align__(16) float sm[SMEM];
  const int tid  = threadIdx.x;
  const int lane = tid & 63;
  const int Q    = tid >> 6;
  const int n15  = lane & 15;          // MFMA: A-row m / B-col n / D-col
  const int q4   = lane >> 4;          // MFMA: k-group / D-row quad
  const int w0   = blockIdx.x * 16;
  const int h0   = blockIdx.y * 16;
  const int bz   = blockIdx.z;
  const int bb   = bz / ZCH;
  const int d_lo = (bz % ZCH) * DC;

  // zero raw region + zrow (invalid halo stays 0 forever)
  for (int i = tid; i < ZEND; i += 256) sm[i] = 0.f;

  // shared banded selection fragment: SEL[j] = [n15 <= k <= n15+8], k = 8*q4+j
  half8 SEL;
  #pragma unroll
  for (int j = 0; j < 8; ++j) {
    const int k = 8*q4 + j;
    SEL[j] = (k >= n15 && k <= n15 + 8) ? (_Float16)1 : (_Float16)0;
  }

  // ---------- staging: 288 tasks = 2 slc x 24 r x 6 quads ----------
  bool val0 = false, val1 = false;
  int  lo0 = 0, lo1 = 0, sc0 = 0, sc1 = 0;
  const float *pi0 = gI, *pj0 = gJ, *pi1 = gI, *pj1 = gJ;
  {
    auto prep = [&](int t, bool& val, int& lo, int& sc,
                    const float*& pi, const float*& pj) {
      if (t >= 288) { val = false; return; }
      sc = t / 144;
      const int u = t - sc*144;
      const int r = u / 6, c = u - r*6;
      const int gh = h0 - 4 + r, gw = w0 - 4 + 4*c;
      val = ((unsigned)gh < (unsigned)H_) && (gw >= 0) && (gw + 3 < W_);
      lo  = sc*SLS + r*RS + 2*c;
      const long off = ((long)(bb*D_ + (d_lo - 4 + sc))*H_ + gh)*(long)W_ + gw;
      pi = gI + off; pj = gJ + off;
    };
    prep(tid, val0, lo0, sc0, pi0, pj0);
    prep((tid >= 224) ? tid + 32 : 512, val1, lo1, sc1, pi1, pj1);
  }

  // ---------- chain bases: wave Q handles c = Q, Q+4, Q+8 (<10) ----------
  int rb_[3], hb_[3];
  #pragma unroll
  for (int i = 0; i < 3; ++i) {
    int c = Q + 4*i; if (c > 9) c = 9;          // clamped entry unused
    rb_[i] = (c % 5)*FS + (c / 5)*SLS;
    hb_[i] = HSUM0 + c*HCS;
  }
  const int a1r = n15*RS + 4*q4;
  const int a2r = (n15 < 8) ? ((16 + n15)*RS + 4*q4) : -1;
  const int zr  = ZROW + 4*q4;

  // ---------- ring: thread owns (h = tid>>4, w = tid&15) ----------
  const int rh = tid >> 4, rw = tid & 15;
  const int rbase = HSUM0 + rw*HRS + (rh >> 1);
  const int rsh   = (rh & 1) * 16;

  float ring[5][9], S[5];
  #pragma unroll
  for (int f = 0; f < 5; ++f) {
    S[f] = 0.f;
    #pragma unroll
    for (int k = 0; k < 9; ++k) ring[f][k] = 0.f;
  }
  float acc = 0.f;

  // ---------- global prefetch ----------
  float4 f0i = {0,0,0,0}, f0j = {0,0,0,0}, f1i = {0,0,0,0}, f1j = {0,0,0,0};
  auto fetch = [&](int sbase) {
    if (val0 && (unsigned)(sbase + sc0) < (unsigned)D_) {
      f0i = *(const float4*)pi0; f0j = *(const float4*)pj0;
    } else { f0i = make_float4(0,0,0,0); f0j = make_float4(0,0,0,0); }
    pi0 += 2*HW_; pj0 += 2*HW_;
    if (val1 && (unsigned)(sbase + sc1) < (unsigned)D_) {
      f1i = *(const float4*)pi1; f1j = *(const float4*)pj1;
    } else { f1i = make_float4(0,0,0,0); f1j = make_float4(0,0,0,0); }
    pi1 += 2*HW_; pj1 += 2*HW_;
  };

  auto stage_one = [&](int lo, float4 fi, float4 fj) {
    const __half2 i01 = __floats2half2_rn(fi.x, fi.y);
    const __half2 i23 = __floats2half2_rn(fi.z, fi.w);
    const __half2 j01 = __floats2half2_rn(fj.x, fj.y);
    const __half2 j23 = __floats2half2_rn(fj.z, fj.w);
    HP hI; hI.a = i01; hI.b = i23;
    HP hJ; hJ.a = j01; hJ.b = j23;
    HP h2; h2.a = __hmul2(i01, i01); h2.b = __hmul2(i23, i23);
    HP h3; h3.a = __hmul2(j01, j01); h3.b = __hmul2(j23, j23);
    HP h4; h4.a = __hmul2(i01, j01); h4.b = __hmul2(i23, j23);
    *(HP*)&sm[lo]        = hI;
    *(HP*)&sm[lo +   FS] = hJ;
    *(HP*)&sm[lo + 2*FS] = h2;
    *(HP*)&sm[lo + 3*FS] = h3;
    *(HP*)&sm[lo + 4*FS] = h4;
  };
  auto stage_write = [&]() {
    if (val0) stage_one(lo0, f0i, f0j);
    if (val1) stage_one(lo1, f1i, f1j);
  };

  // ---- one chain: raw field slice -> hsum (3 MFMAs, transpose in-register) ----
  // wsum D-layout: lane(n15,q4) elem r = wsum[row 4q4+r][col n15] (d1: rows
  // 0..15, d2: rows 16..23, zero for rows 24..31). h-MFMA B needs lane(n15,q4)
  // = wsum[k=8q4..8q4+7][col n15]. Per dword slot i: swap32(t_i,u_i) then
  // swap16(t_i,u_i) -> t_i = B_lo dword i, u_i = B_hi dword i. Rows 24..31
  // arrive as d2's zero rows; SEL[m][k]=0 for k>=24 anyway.
  auto chain = [&](int rb, int hb) {
    const half8 A1 = *(const half8*)&sm[rb + a1r];
    const half8 A2 = (a2r >= 0) ? *(const half8*)&sm[rb + a2r]
                                : *(const half8*)&sm[zr];
    const f32x4 z = {0.f, 0.f, 0.f, 0.f};
    const f32x4 d1 = MFMA16(A1, SEL, z);      // wsum rows 0..15
    const f32x4 d2 = MFMA16(A2, SEL, z);      // wsum rows 16..23 (24..31 = 0)
    unsigned t0 = __builtin_bit_cast(unsigned, __floats2half2_rn(d1[0], d1[1]));
    unsigned t1 = __builtin_bit_cast(unsigned, __floats2half2_rn(d1[2], d1[3]));
    unsigned u0 = __builtin_bit_cast(unsigned, __floats2half2_rn(d2[0], d2[1]));
    unsigned u1 = __builtin_bit_cast(unsigned, __floats2half2_rn(d2[2], d2[3]));
    PL32(t0, u0);                             // t0=[D1|D2 lo-halves], u0=[hi]
    PL32(t1, u1);
    PL16(t0, u0);                             // t0=B_lo dw0, u0=B_hi dw0
    PL16(t1, u1);                             // t1=B_lo dw1, u1=B_hi dw1
    union { unsigned u[4]; half8 h; } Bv;
    Bv.u[0] = t0; Bv.u[1] = t1; Bv.u[2] = u0; Bv.u[3] = u1;
    const f32x4 dh = MFMA16(SEL, Bv.h, z);    // hsum[m = h][n = w]
    HP ph; ph.a = __floats2half2_rn(dh[0], dh[1]); ph.b = __floats2half2_rn(dh[2], dh[3]);
    *(HP*)&sm[hb + n15*HRS + 2*q4] = ph;      // col w = n15, h = 4q4..4q4+3
  };

  auto h2ext = [&](int addr) -> float {
    const unsigned u = *(const unsigned*)&sm[addr];
    return __half2float(__ushort_as_half((unsigned short)(u >> rsh)));
  };
  auto ring_cc = [&](int m) {
    float nA[5], nB[5];
    #pragma unroll
    for (int f = 0; f < 5; ++f) {
      nA[f] = h2ext(rbase + f*HCS);           // slice A = chain f
      nB[f] = h2ext(rbase + (5 + f)*HCS);     // slice B = chain 5+f
    }
    float SA[5], SB[5];
    #pragma unroll
    for (int f = 0; f < 5; ++f) {
      SA[f] = S[f]  + nA[f] - ring[f][8];
      SB[f] = SA[f] + nB[f] - ring[f][7];
      S[f]  = SB[f];
      #pragma unroll
      for (int k = 8; k >= 2; --k) ring[f][k] = ring[f][k-2];
      ring[f][1] = nA[f]; ring[f][0] = nB[f];
    }
    if (m >= 4) {
      {
        const float cr = SA[4] - SA[0]*SA[1]*W3I;
        const float vi = SA[2] - SA[0]*SA[0]*W3I;
        const float vj = SA[3] - SA[1]*SA[1]*W3I;
        acc += cr*cr * RCP(vi*vj + 1e-5f);
      }
      {
        const float cr = SB[4] - SB[0]*SB[1]*W3I;
        const float vi = SB[2] - SB[0]*SB[0]*W3I;
        const float vj = SB[3] - SB[1]*SB[1]*W3I;
        acc += cr*cr * RCP(vi*vj + 1e-5f);
      }
    }
  };

  fetch(d_lo - 4);          // macro 0 slices
  __syncthreads();          // zero-init visible
  stage_write();            // raw macro 0
  fetch(d_lo - 2);          // macro 1 slices
  __syncthreads();          // raw 0 ready

  for (int m = 0; m < NMAC; ++m) {
    chain(rb_[0], hb_[0]);
    chain(rb_[1], hb_[1]);
    if (Q < 2) chain(rb_[2], hb_[2]);
    __syncthreads();                       // hsum (all waves) ready
    if (m + 1 < NMAC) { stage_write(); fetch(d_lo + 2*m); }  // raw m+1; regs m+2
    ring_cc(m);
    __syncthreads();                       // raw m+1 ready; hsum consumed
  }

  // ---- block reduction -> single atomic ----
  float v = acc;
  #pragma unroll
  for (int off = 32; off > 0; off >>= 1)
    v += __shfl_down(v, off, 64);
  if (lane == 0) sm[REDU + Q] = v;
  __syncthreads();
  if (tid == 0) {
    const float t = sm[REDU] + sm[REDU+1] + sm[REDU+2] + sm[REDU+3];
    atomicAdd(out, -t / NTOT);
  }
}

extern "C" void kernel_launch(void* const* d_in, const int* in_sizes, int n_in,
                              void* d_out, int out_size, void* d_ws, size_t ws_size,
                              hipStream_t stream) {
  const float* J = (const float*)d_in[0];  // y_pred
  const float* I = (const float*)d_in[1];  // y_true (cc symmetric in I,J)
  float* outp = (float*)d_out;
  hipMemsetAsync(d_out, 0, sizeof(float), stream);
  dim3 grid(W_/16, H_/16, B_*ZCH);         // 10 x 12 x 8 = 960 blocks
  ncc_fused<<<grid, dim3(256), 0, stream>>>(I, J, outp);
}